// Round 2
// baseline (1213.274 us; speedup 1.0000x reference)
//
#include <hip/hip_runtime.h>
#include <math.h>

#define T_STEPS 64
#define BATCH   512

typedef short s16x8 __attribute__((ext_vector_type(8)));
typedef float f32x4 __attribute__((ext_vector_type(4)));

#define MFMA(a,b,c) __builtin_amdgcn_mfma_f32_16x16x32_bf16((a),(b),(c),0,0,0)

__device__ __forceinline__ short f2bf(float x){
    union { float f; unsigned u; } v; v.f = x;
    unsigned r = v.u + 0x7FFFu + ((v.u >> 16) & 1u);
    return (short)(r >> 16);
}
__device__ __forceinline__ float bf2f(short s){
    union { unsigned u; float f; } v; v.u = ((unsigned)(unsigned short)s) << 16;
    return v.f;
}
__device__ __forceinline__ float frcp(float x){ return __builtin_amdgcn_rcpf(x); }
__device__ __forceinline__ float fsig(float x){ return frcp(1.f + __expf(-x)); }
__device__ __forceinline__ float ftanh(float x){ return 1.f - 2.f*frcp(1.f + __expf(2.f*x)); }
__device__ __forceinline__ float sp(float x){ return (x>20.f)? x : __logf(1.f + __expf(x)); }

// raw barrier: LDS-fence only; vmcnt stays outstanding (stores/prefetch float across)
__device__ __forceinline__ void barx(){
    __builtin_amdgcn_sched_barrier(0);
    asm volatile("s_waitcnt lgkmcnt(0)" ::: "memory");
    __builtin_amdgcn_s_barrier();
    __builtin_amdgcn_sched_barrier(0);
}

// ---- packed fragment bases (fragment = 64 lanes x 8 bf16 = 1024B) ----
// frag index = base + nt*KT + kt ; elem e of lane l: W[k0 + kt*32+(l>>4)*8+e][nt*16+(l&15)]
#define FR_GRUX 0      // w_gru rows 0:200    K=200(7)  N=600(38) -> 266
#define FR_GRUD 266    // w_gru rows 200:400  K=200(7)  N=600(38) -> 266
#define FR_INP  532    // w_inp   K=36(2)   N=200(13) -> 26
#define FR_OBSD 558    // w_obsout rows 0:200   K=200(7)  N=200(13) -> 91
#define FR_OBSE 649    // w_obsout rows 200:    K=1024(32) N=200(13) -> 416
#define FR_OBS  1065   // w_obs   K=200(7)  N=60(4)  -> 28
#define FR_IMG  1093   // w_imgout K=200(7) N=200(13) -> 91
#define FR_IMS  1184   // w_ims   K=200(7)  N=60(4)  -> 28
#define FR_TOT  1212

// ws byte offsets
#define WS_STOCH0 1241088
#define WS_DETER0 1241216
#define WS_E      1242112   // bf16 E[32768][200]

__global__ void pack_kernel(const float* w_inp, const float* w_gru, const float* w_imgout,
                            const float* w_obsout, const float* w_ims, const float* w_obs,
                            short* pk){
    int f = blockIdx.x, l = threadIdx.x;
    const float* W; int K, N, ld, KT, k0, rel;
    if      (f < FR_GRUD){ W=w_gru;    K=200; N=600; ld=600; KT=7;  k0=0;   rel=f; }
    else if (f < FR_INP ){ W=w_gru;    K=200; N=600; ld=600; KT=7;  k0=200; rel=f-FR_GRUD; }
    else if (f < FR_OBSD){ W=w_inp;    K=36;  N=200; ld=200; KT=2;  k0=0;   rel=f-FR_INP; }
    else if (f < FR_OBSE){ W=w_obsout; K=200; N=200; ld=200; KT=7;  k0=0;   rel=f-FR_OBSD; }
    else if (f < FR_OBS ){ W=w_obsout; K=1024;N=200; ld=200; KT=32; k0=200; rel=f-FR_OBSE; }
    else if (f < FR_IMG ){ W=w_obs;    K=200; N=60;  ld=60;  KT=7;  k0=0;   rel=f-FR_OBS; }
    else if (f < FR_IMS ){ W=w_imgout; K=200; N=200; ld=200; KT=7;  k0=0;   rel=f-FR_IMG; }
    else                 { W=w_ims;    K=200; N=60;  ld=60;  KT=7;  k0=0;   rel=f-FR_IMS; }
    int nt = rel / KT, kt = rel % KT;
    int col = nt*16 + (l & 15);
    int kb  = kt*32 + (l >> 4)*8;
    s16x8 v;
    #pragma unroll
    for (int e = 0; e < 8; e++){
        int k = kb + e;
        float x = (k < K && col < N) ? W[(size_t)(k + k0)*ld + col] : 0.f;
        v[e] = f2bf(x);
    }
    *(((s16x8*)pk) + (size_t)f*64 + l) = v;
}

__global__ void init_kernel(const float* w_init, const float* w_imgout,
                            const float* ln_img_s, const float* ln_img_b,
                            const float* w_ims, const float* b_ims,
                            float* stoch0, float* deter0){
    __shared__ float d0[200], h0[200], redA[64], redB[64], mv[2];
    int t = threadIdx.x;
    if (t < 200) d0[t] = tanhf(w_init[t]);
    __syncthreads();
    if (t < 200){ float a = 0.f; for (int k = 0; k < 200; k++) a += d0[k]*w_imgout[k*200 + t]; h0[t] = a; }
    __syncthreads();
    if (t < 64){ float s = 0.f, s2 = 0.f;
        for (int j = t; j < 200; j += 64){ float v = h0[j]; s += v; s2 += v*v; }
        redA[t] = s; redB[t] = s2; }
    __syncthreads();
    if (t == 0){ float s = 0.f, s2 = 0.f;
        for (int i = 0; i < 64; i++){ s += redA[i]; s2 += redB[i]; }
        float m = s/200.f, var = s2/200.f - m*m;
        mv[0] = m; mv[1] = rsqrtf(var + 1e-3f); }
    __syncthreads();
    if (t < 200){ float v = (h0[t]-mv[0])*mv[1]*ln_img_s[t] + ln_img_b[t];
        h0[t] = v/(1.f+expf(-v)); }
    __syncthreads();
    if (t < 200) deter0[t] = d0[t];
    if (t < 30){ float a = 0.f; for (int j = 0; j < 200; j++) a += h0[j]*w_ims[j*60 + t];
        stoch0[t] = a + b_ims[t]; }
}

// E[t,b,:] = embed[t,b,:] @ w_obsout[200:1224,:]   (bf16 result)
__global__ __launch_bounds__(256) void embed_gemm(const float* embed, const short* pk, short* E){
    int tid = threadIdx.x; int w = tid >> 6, l = tid & 63;
    int row0 = blockIdx.x*128 + w*32;
    const float* A0 = embed + (size_t)(row0 + (l & 15))*1024 + (l >> 4)*8;
    const float* A1 = A0 + (size_t)16*1024;
    const s16x8* B = ((const s16x8*)pk) + (size_t)FR_OBSE*64 + l;
    f32x4 acc0[13], acc1[13];
    #pragma unroll
    for (int n = 0; n < 13; n++){ acc0[n] = (f32x4){0.f,0.f,0.f,0.f}; acc1[n] = (f32x4){0.f,0.f,0.f,0.f}; }
    for (int kt = 0; kt < 32; kt++){
        float4 x0 = *(const float4*)(A0 + kt*32), x1 = *(const float4*)(A0 + kt*32 + 4);
        float4 y0 = *(const float4*)(A1 + kt*32), y1 = *(const float4*)(A1 + kt*32 + 4);
        s16x8 af0, af1;
        af0[0]=f2bf(x0.x); af0[1]=f2bf(x0.y); af0[2]=f2bf(x0.z); af0[3]=f2bf(x0.w);
        af0[4]=f2bf(x1.x); af0[5]=f2bf(x1.y); af0[6]=f2bf(x1.z); af0[7]=f2bf(x1.w);
        af1[0]=f2bf(y0.x); af1[1]=f2bf(y0.y); af1[2]=f2bf(y0.z); af1[3]=f2bf(y0.w);
        af1[4]=f2bf(y1.x); af1[5]=f2bf(y1.y); af1[6]=f2bf(y1.z); af1[7]=f2bf(y1.w);
        #pragma unroll
        for (int n = 0; n < 13; n++){
            s16x8 bf = B[(n*32 + kt)*64];
            acc0[n] = MFMA(af0, bf, acc0[n]);
            acc1[n] = MFMA(af1, bf, acc1[n]);
        }
    }
    int rr = (l >> 4)*4, cc = l & 15;
    #pragma unroll
    for (int n = 0; n < 13; n++){
        int col = n*16 + cc;
        if (col < 200){
            #pragma unroll
            for (int r = 0; r < 4; r++){
                E[(size_t)(row0 + rr + r)*200 + col]        = f2bf(acc0[n][r]);
                E[(size_t)(row0 + 16 + rr + r)*200 + col]   = f2bf(acc1[n][r]);
            }
        }
    }
}

#define ABS_ 424   // bf16: cols 0:200 x, 200:400 deter, 400:424 zero  (848B/16 odd)
#define PBS  612   // bf16 parts, conflict-free row groups
#define U1S  210   // f32 xpre/hpre
#define HOS  232   // bf16 ho (pad 200:232 zero)
#define U3S  68    // f32 qpre

__global__ __launch_bounds__(512) void scan_kernel(
    const float* __restrict__ action, const float* __restrict__ is_first,
    const float* __restrict__ noise_post,
    const float* __restrict__ ln_inp_s, const float* __restrict__ ln_inp_b,
    const float* __restrict__ ln_obs_s, const float* __restrict__ ln_obs_b,
    const float* __restrict__ b_obs,
    const short* __restrict__ pk, const short* __restrict__ E,
    const float* __restrict__ stoch0g, const float* __restrict__ deter0g,
    float* __restrict__ out)
{
    __shared__ short Abuf[16*ABS_];   // 13568
    __shared__ short Pb[16*PBS];      // 19584
    __shared__ float U1[16*U1S];      // 13440
    __shared__ short A36[16*64];      // 2048
    __shared__ short Ho[16*HOS];      // 7424
    __shared__ float U3[16*U3S];      // 4352
    __shared__ float Sbuf[16*30];     // 1920   => 62336 B total

    const int tid = threadIdx.x;
    const int w = tid >> 6, l = tid & 63;
    const int hrow = tid >> 5, s = tid & 31;
    const int r0 = blockIdx.x*16;
    const int rr = (l>>4)*4, cc = l&15;
    const s16x8* PK = (const s16x8*)pk;

    // ---- hoisted params ----
    float lis[7], lib[7], los[7], lob[7], d0r[7], dreg[7];
    #pragma unroll
    for (int i=0;i<7;i++){ int j=s+32*i; bool ok = j<200;
        lis[i]= ok? ln_inp_s[j]:0.f; lib[i]= ok? ln_inp_b[j]:0.f;
        los[i]= ok? ln_obs_s[j]:0.f; lob[i]= ok? ln_obs_b[j]:0.f;
        d0r[i]= ok? deter0g[j]:0.f;  dreg[i]=d0r[i];
    }
    float st0 = (s<30)? stoch0g[s] : 0.f;
    float bo0 = (s<30)? b_obs[s] : 0.f;
    float bo1 = (s<30)? b_obs[30+s] : 0.f;

    // ---- hoisted weights: mm3 nt=w ; mm4 nt=w-4 (w>=4) ----
    s16x8 Bm3a[7], Bm4[7];
    #pragma unroll
    for (int kt=0;kt<7;kt++) Bm3a[kt] = PK[(size_t)(FR_OBSD + w*7 + kt)*64 + l];
    if (w>=4){
        #pragma unroll
        for (int kt=0;kt<7;kt++) Bm4[kt] = PK[(size_t)(FR_OBS + (w-4)*7 + kt)*64 + l];
    }

    // ---- init LDS ----
    #pragma unroll
    for (int i=0;i<7;i++){ int j=s+32*i; if (j<200) Abuf[hrow*ABS_+200+j] = f2bf(d0r[i]); }
    if (s<30) Sbuf[hrow*30+s] = st0;
    for (int idx=tid; idx<16*24; idx+=512) Abuf[(idx/24)*ABS_ + 400 + (idx%24)] = 0;
    for (int idx=tid; idx<16*28; idx+=512) A36[(idx/28)*64 + 36 + (idx%28)] = 0;
    for (int idx=tid; idx<16*32; idx+=512) Ho[(idx/32)*HOS + 200 + (idx%32)] = 0;

    // initial t=0 input loads
    const int aj = (s>=30)? (s-30) : (s<4 ? s+2 : -1);
    float f_cur = is_first[r0 + hrow];
    float act_cur = 0.f;
    if (aj>=0) act_cur = action[(size_t)(r0+hrow)*6 + aj];

    barx();

    for (int t=0; t<T_STEPS; t++){
        const size_t gr = (size_t)t*BATCH + r0;
        // ---- S0: is_first masking + A36 + prefetches ----
        float f = f_cur;
        if (f != 0.f){
            #pragma unroll
            for (int i=0;i<7;i++){ int j=s+32*i; if (j<200){
                dreg[i]=d0r[i]; Abuf[hrow*ABS_+200+j]=f2bf(d0r[i]); } }
        }
        {
            float v;
            if (s<30) v = (f!=0.f)? st0 : Sbuf[hrow*30+s];
            else { float a = act_cur; a = a*frcp(fmaxf(fabsf(a),1.f)); v = (f!=0.f)?0.f:a; }
            A36[hrow*64 + s] = f2bf(v);
            if (s<4){
                float a = act_cur; a = a*frcp(fmaxf(fabsf(a),1.f));
                A36[hrow*64 + 32 + s] = f2bf((f!=0.f)?0.f:a);
            }
        }
        // current-step prefetches (consumed S5/S8)
        float nz = 0.f;
        if (s<30) nz = noise_post[(gr + hrow)*30 + s];
        short EA[4], EB[4];
        {
            int colA = w*16 + cc;
            #pragma unroll
            for (int r=0;r<4;r++) EA[r] = E[(gr + rr + r)*200 + colA];
        }
        if (w<5){
            int colB = 128 + w*16 + cc;
            #pragma unroll
            for (int r=0;r<4;r++) EB[r] = (colB<200)? E[(gr + rr + r)*200 + colB] : (short)0;
        }
        // next-step prefetch
        {
            int tn = (t<T_STEPS-1)? t+1 : t;
            size_t grn = (size_t)tn*BATCH + r0;
            f_cur = is_first[grn + hrow];
            if (aj>=0) act_cur = action[(grn + hrow)*6 + aj];
        }
        barx(); // B1

        // ---- S1: mm2a deter@GRUD (all waves) + mm1 (waves 6,7) ----
        {
            s16x8 ad[7];
            #pragma unroll
            for (int kt=0;kt<7;kt++) ad[kt] = *(const s16x8*)&Abuf[cc*ABS_ + 200 + kt*32 + (l>>4)*8];
            #pragma unroll
            for (int it=0; it<5; it++){
                int nt = w + it*8;
                if (nt < 38){
                    const s16x8* B = PK + (size_t)(FR_GRUD + nt*7)*64 + l;
                    f32x4 a0={0.f,0.f,0.f,0.f}, a1={0.f,0.f,0.f,0.f};
                    a0 = MFMA(ad[0], B[0*64], a0);
                    a1 = MFMA(ad[1], B[1*64], a1);
                    a0 = MFMA(ad[2], B[2*64], a0);
                    a1 = MFMA(ad[3], B[3*64], a1);
                    a0 = MFMA(ad[4], B[4*64], a0);
                    a1 = MFMA(ad[5], B[5*64], a1);
                    a0 = MFMA(ad[6], B[6*64], a0);
                    #pragma unroll
                    for (int r=0;r<4;r++) Pb[(rr+r)*PBS + nt*16 + cc] = f2bf(a0[r]+a1[r]);
                }
            }
            if (w >= 6){
                s16x8 a0v = *(const s16x8*)&A36[cc*64 + (l>>4)*8];
                s16x8 a1v = *(const s16x8*)&A36[cc*64 + 32 + (l>>4)*8];
                #pragma unroll
                for (int it=0; it<7; it++){
                    int nt = (w-6) + it*2;
                    if (nt < 13){
                        const s16x8* B = PK + (size_t)(FR_INP + nt*2)*64 + l;
                        f32x4 acc={0.f,0.f,0.f,0.f};
                        acc = MFMA(a0v, B[0],  acc);
                        acc = MFMA(a1v, B[64], acc);
                        #pragma unroll
                        for (int r=0;r<4;r++) U1[(rr+r)*U1S + nt*16 + cc] = acc[r];
                    }
                }
            }
        }
        barx(); // B2

        // ---- S2: LN(inp)+silu -> Abuf x ----
        {
            float vals[7], sum=0.f, sq=0.f;
            #pragma unroll
            for (int i=0;i<7;i++){ int j=s+32*i;
                float v = (j<200)? U1[hrow*U1S + j] : 0.f;
                vals[i]=v; sum+=v; sq+=v*v; }
            #pragma unroll
            for (int m=16;m>=1;m>>=1){ sum += __shfl_xor(sum,m); sq += __shfl_xor(sq,m); }
            float mean = sum*(1.f/200.f);
            float var  = sq*(1.f/200.f) - mean*mean;
            float rstd = rsqrtf(var + 1e-3f);
            #pragma unroll
            for (int i=0;i<7;i++){ int j=s+32*i; if (j<200){
                float v = (vals[i]-mean)*rstd*lis[i] + lib[i];
                Abuf[hrow*ABS_ + j] = f2bf(v*fsig(v));
            }}
        }
        barx(); // B3

        // ---- S3: mm2b x@GRUX accumulating onto Pb ----
        {
            s16x8 ax[7];
            #pragma unroll
            for (int kt=0;kt<7;kt++) ax[kt] = *(const s16x8*)&Abuf[cc*ABS_ + kt*32 + (l>>4)*8];
            #pragma unroll
            for (int it=0; it<5; it++){
                int nt = w + it*8;
                if (nt < 38){
                    const s16x8* B = PK + (size_t)(FR_GRUX + nt*7)*64 + l;
                    f32x4 a0, a1={0.f,0.f,0.f,0.f};
                    #pragma unroll
                    for (int r=0;r<4;r++) a0[r] = bf2f(Pb[(rr+r)*PBS + nt*16 + cc]);
                    a0 = MFMA(ax[0], B[0*64], a0);
                    a1 = MFMA(ax[1], B[1*64], a1);
                    a0 = MFMA(ax[2], B[2*64], a0);
                    a1 = MFMA(ax[3], B[3*64], a1);
                    a0 = MFMA(ax[4], B[4*64], a0);
                    a1 = MFMA(ax[5], B[5*64], a1);
                    a0 = MFMA(ax[6], B[6*64], a0);
                    #pragma unroll
                    for (int r=0;r<4;r++) Pb[(rr+r)*PBS + nt*16 + cc] = f2bf(a0[r]+a1[r]);
                }
            }
        }
        barx(); // B4

        // ---- S4: GRU elementwise ----
        {
            float* outp = out + (gr + hrow)*380 + 180;
            #pragma unroll
            for (int i=0;i<7;i++){ int j=s+32*i; if (j<200){
                float rv = bf2f(Pb[hrow*PBS + j]);
                float cv = bf2f(Pb[hrow*PBS + 200 + j]);
                float uv = bf2f(Pb[hrow*PBS + 400 + j]);
                float rg = fsig(rv);
                float cg = ftanh(rg*cv);
                float ug = fsig(uv - 1.f);
                float d  = ug*cg + (1.f-ug)*dreg[i];
                dreg[i] = d;
                Abuf[hrow*ABS_ + 200 + j] = f2bf(d);
                outp[j] = d;
            }}
        }
        barx(); // B5

        // ---- S5: mm3 deter@OBSD, C-init = E ----
        {
            s16x8 Bb[7];
            if (w<5){
                #pragma unroll
                for (int kt=0;kt<7;kt++) Bb[kt] = PK[(size_t)(FR_OBSD + (8+w)*7 + kt)*64 + l];
            }
            s16x8 ad[7];
            #pragma unroll
            for (int kt=0;kt<7;kt++) ad[kt] = *(const s16x8*)&Abuf[cc*ABS_ + 200 + kt*32 + (l>>4)*8];
            {
                f32x4 a0, a1={0.f,0.f,0.f,0.f};
                #pragma unroll
                for (int r=0;r<4;r++) a0[r] = bf2f(EA[r]);
                a0 = MFMA(ad[0], Bm3a[0], a0);
                a1 = MFMA(ad[1], Bm3a[1], a1);
                a0 = MFMA(ad[2], Bm3a[2], a0);
                a1 = MFMA(ad[3], Bm3a[3], a1);
                a0 = MFMA(ad[4], Bm3a[4], a0);
                a1 = MFMA(ad[5], Bm3a[5], a1);
                a0 = MFMA(ad[6], Bm3a[6], a0);
                #pragma unroll
                for (int r=0;r<4;r++) U1[(rr+r)*U1S + w*16 + cc] = a0[r]+a1[r];
            }
            if (w<5){
                f32x4 a0, a1={0.f,0.f,0.f,0.f};
                #pragma unroll
                for (int r=0;r<4;r++) a0[r] = bf2f(EB[r]);
                a0 = MFMA(ad[0], Bb[0], a0);
                a1 = MFMA(ad[1], Bb[1], a1);
                a0 = MFMA(ad[2], Bb[2], a0);
                a1 = MFMA(ad[3], Bb[3], a1);
                a0 = MFMA(ad[4], Bb[4], a0);
                a1 = MFMA(ad[5], Bb[5], a1);
                a0 = MFMA(ad[6], Bb[6], a0);
                #pragma unroll
                for (int r=0;r<4;r++) U1[(rr+r)*U1S + (8+w)*16 + cc] = a0[r]+a1[r];
            }
        }
        barx(); // B6

        // ---- S6: LN(obs)+silu -> Ho ----
        {
            float vals[7], sum=0.f, sq=0.f;
            #pragma unroll
            for (int i=0;i<7;i++){ int j=s+32*i;
                float v = (j<200)? U1[hrow*U1S + j] : 0.f;
                vals[i]=v; sum+=v; sq+=v*v; }
            #pragma unroll
            for (int m=16;m>=1;m>>=1){ sum += __shfl_xor(sum,m); sq += __shfl_xor(sq,m); }
            float mean = sum*(1.f/200.f);
            float var  = sq*(1.f/200.f) - mean*mean;
            float rstd = rsqrtf(var + 1e-3f);
            #pragma unroll
            for (int i=0;i<7;i++){ int j=s+32*i; if (j<200){
                float v = (vals[i]-mean)*rstd*los[i] + lob[i];
                Ho[hrow*HOS + j] = f2bf(v*fsig(v));
            }}
        }
        barx(); // B7

        // ---- S7: mm4 ho@OBS (waves 4..7) ----
        if (w>=4){
            s16x8 ah[7];
            #pragma unroll
            for (int kt=0;kt<7;kt++) ah[kt] = *(const s16x8*)&Ho[cc*HOS + kt*32 + (l>>4)*8];
            f32x4 a0={0.f,0.f,0.f,0.f}, a1={0.f,0.f,0.f,0.f};
            a0 = MFMA(ah[0], Bm4[0], a0);
            a1 = MFMA(ah[1], Bm4[1], a1);
            a0 = MFMA(ah[2], Bm4[2], a0);
            a1 = MFMA(ah[3], Bm4[3], a1);
            a0 = MFMA(ah[4], Bm4[4], a0);
            a1 = MFMA(ah[5], Bm4[5], a1);
            a0 = MFMA(ah[6], Bm4[6], a0);
            int nt = w-4;
            #pragma unroll
            for (int r=0;r<4;r++) U3[(rr+r)*U3S + nt*16 + cc] = a0[r]+a1[r];
        }
        barx(); // B8

        // ---- S8: posterior stats + carry ----
        if (s<30){
            float qm = U3[hrow*U3S + s] + bo0;
            float x  = U3[hrow*U3S + 30 + s] + bo1;
            float qs = sp(x) + 0.1f;
            float post = qm + qs*nz;
            float* op = out + (gr + hrow)*380;
            op[s]=qm; op[30+s]=qs; op[60+s]=post;
            Sbuf[hrow*30+s]=post;
        }
        barx(); // B9
    }
}

// prior head for all (t,b)
__global__ __launch_bounds__(64) void prior_kernel(const float* noise_prior, const float* b_ims,
                                                   const float* ln_img_s, const float* ln_img_b,
                                                   const short* pk, float* out){
    __shared__ short Ab[16*232];
    __shared__ float U[16*212];
    __shared__ short hob[16*224];
    __shared__ float qp[16*68];
    int l = threadIdx.x;
    int g0 = blockIdx.x*16;

    for (int idx = l; idx < 16*232; idx += 64){
        int rr = idx/232, c = idx%232;
        short v = 0;
        if (c < 200) v = f2bf(out[(size_t)(g0 + rr)*380 + 180 + c]);
        Ab[idx] = v;
    }
    __syncthreads();
    {
        s16x8 af[7];
        #pragma unroll
        for (int kt = 0; kt < 7; kt++)
            af[kt] = *(s16x8*)&Ab[(l & 15)*232 + kt*32 + (l >> 4)*8];
        for (int nt = 0; nt < 13; nt++){
            f32x4 acc = (f32x4){0.f,0.f,0.f,0.f};
            const s16x8* B = ((const s16x8*)pk) + (size_t)(FR_IMG + nt*7)*64 + l;
            #pragma unroll
            for (int kt = 0; kt < 7; kt++) acc = MFMA(af[kt], B[kt*64], acc);
            int rr = (l >> 4)*4, cc = l & 15;
            #pragma unroll
            for (int r = 0; r < 4; r++) U[(rr + r)*212 + nt*16 + cc] = acc[r];
        }
    }
    __syncthreads();
    {
        int rw = l >> 2, s4 = l & 3;
        float sum = 0.f, sq = 0.f, vals[50];
        #pragma unroll
        for (int i = 0; i < 50; i++){ int j = s4 + 4*i; float v = U[rw*212 + j];
            vals[i] = v; sum += v; sq += v*v; }
        sum += __shfl_xor(sum, 1); sq += __shfl_xor(sq, 1);
        sum += __shfl_xor(sum, 2); sq += __shfl_xor(sq, 2);
        float mean = sum/200.f, var = sq/200.f - mean*mean, rstd = rsqrtf(var + 1e-3f);
        #pragma unroll
        for (int i = 0; i < 50; i++){ int j = s4 + 4*i;
            float v = (vals[i] - mean)*rstd*ln_img_s[j] + ln_img_b[j];
            hob[rw*224 + j] = f2bf(v*fsig(v));
        }
    }
    for (int idx = l; idx < 16*24; idx += 64){ int rr = idx/24; hob[rr*224 + 200 + idx%24] = 0; }
    __syncthreads();
    for (int nt = 0; nt < 4; nt++){
        s16x8 af[7];
        #pragma unroll
        for (int kt = 0; kt < 7; kt++)
            af[kt] = *(s16x8*)&hob[(l & 15)*224 + kt*32 + (l >> 4)*8];
        f32x4 acc = (f32x4){0.f,0.f,0.f,0.f};
        const s16x8* B = ((const s16x8*)pk) + (size_t)(FR_IMS + nt*7)*64 + l;
        #pragma unroll
        for (int kt = 0; kt < 7; kt++) acc = MFMA(af[kt], B[kt*64], acc);
        int rr = (l >> 4)*4, cc = l & 15;
        #pragma unroll
        for (int r = 0; r < 4; r++) qp[(rr + r)*68 + nt*16 + cc] = acc[r];
    }
    __syncthreads();
    for (int idx = l; idx < 480; idx += 64){
        int rw = idx/30, j = idx%30;
        float pm = qp[rw*68 + j] + b_ims[j];
        float x  = qp[rw*68 + 30 + j] + b_ims[30 + j];
        float ps = sp(x) + 0.1f;
        float nz = noise_prior[(size_t)(g0 + rw)*30 + j];
        float prior = pm + ps*nz;
        float* op = out + (size_t)(g0 + rw)*380;
        op[90 + j] = pm; op[120 + j] = ps; op[150 + j] = prior;
    }
}

extern "C" void kernel_launch(void* const* d_in, const int* in_sizes, int n_in,
                              void* d_out, int out_size, void* d_ws, size_t ws_size,
                              hipStream_t stream){
    const float* embed    = (const float*)d_in[0];
    const float* action   = (const float*)d_in[1];
    const float* is_first = (const float*)d_in[2];
    const float* nzp      = (const float*)d_in[3];
    const float* nzq      = (const float*)d_in[4];
    const float* w_inp    = (const float*)d_in[5];
    const float* ln_inp_s = (const float*)d_in[6];
    const float* ln_inp_b = (const float*)d_in[7];
    const float* w_gru    = (const float*)d_in[8];
    const float* w_imgout = (const float*)d_in[9];
    const float* ln_img_s = (const float*)d_in[10];
    const float* ln_img_b = (const float*)d_in[11];
    const float* w_obsout = (const float*)d_in[12];
    const float* ln_obs_s = (const float*)d_in[13];
    const float* ln_obs_b = (const float*)d_in[14];
    const float* w_ims    = (const float*)d_in[15];
    const float* b_ims    = (const float*)d_in[16];
    const float* w_obs    = (const float*)d_in[17];
    const float* b_obs    = (const float*)d_in[18];
    const float* w_init   = (const float*)d_in[19];

    char*  ws     = (char*)d_ws;
    short* pk     = (short*)ws;
    float* stoch0 = (float*)(ws + WS_STOCH0);
    float* deter0 = (float*)(ws + WS_DETER0);
    short* E      = (short*)(ws + WS_E);
    float* out    = (float*)d_out;

    hipLaunchKernelGGL(pack_kernel, dim3(FR_TOT), dim3(64), 0, stream,
                       w_inp, w_gru, w_imgout, w_obsout, w_ims, w_obs, pk);
    hipLaunchKernelGGL(init_kernel, dim3(1), dim3(256), 0, stream,
                       w_init, w_imgout, ln_img_s, ln_img_b, w_ims, b_ims, stoch0, deter0);
    hipLaunchKernelGGL(embed_gemm, dim3(256), dim3(256), 0, stream, embed, pk, E);
    hipLaunchKernelGGL(scan_kernel, dim3(32), dim3(512), 0, stream,
                       action, is_first, nzq, ln_inp_s, ln_inp_b, ln_obs_s, ln_obs_b, b_obs,
                       pk, E, stoch0, deter0, out);
    hipLaunchKernelGGL(prior_kernel, dim3(2048), dim3(64), 0, stream, nzp, b_ims, ln_img_s, ln_img_b, pk, out);
}